// Round 11
// baseline (107.874 us; speedup 1.0000x reference)
//
#include <hip/hip_runtime.h>
#include <hip/hip_bf16.h>

#define NBLK 4096
#define BS 32
#define CH 128

typedef float f32x4 __attribute__((ext_vector_type(4)));
typedef int   i32x4 __attribute__((ext_vector_type(4)));
typedef short bf16x8 __attribute__((ext_vector_type(8)));
typedef unsigned short u16x4 __attribute__((ext_vector_type(4)));

__device__ __forceinline__ short f2b(float x) {
    return __builtin_bit_cast(short, __float2bfloat16(x));
}
__device__ __forceinline__ float b2f(unsigned short h) {
    union { unsigned u; float f; } c; c.u = ((unsigned)h) << 16; return c.f;
}
__device__ __forceinline__ u16x4 pack4(f32x4 a) {
    u16x4 o;
    o[0] = (unsigned short)f2b(a[0]); o[1] = (unsigned short)f2b(a[1]);
    o[2] = (unsigned short)f2b(a[2]); o[3] = (unsigned short)f2b(a[3]);
    return o;
}
__device__ __forceinline__ bf16x8 pack8(f32x4 a, f32x4 b) {
    bf16x8 o;
    o[0] = f2b(a[0]); o[1] = f2b(a[1]); o[2] = f2b(a[2]); o[3] = f2b(a[3]);
    o[4] = f2b(b[0]); o[5] = f2b(b[1]); o[6] = f2b(b[2]); o[7] = f2b(b[3]);
    return o;
}
// swizzled index (shorts) within a [32 rows][32 cols] bf16 head-chunk (2KB)
__device__ __forceinline__ int swz(int row, int col) {
    return (row << 5) + ((((col >> 3) ^ ((row >> 1) & 3)) << 3) | (col & 7));
}

// --- pre-kernel: convert weights to bf16 into workspace -------------------
__global__ void convert_weights(const float* __restrict__ wqkv,
                                const float* __restrict__ wproj,
                                short* __restrict__ wsout) {
    int i = blockIdx.x * 256 + threadIdx.x;          // 0 .. 65535
    if (i < 3 * CH * CH) {
        wsout[i] = f2b(wqkv[i]);
    } else {
        int j = i - 3 * CH * CH;
        if (j < CH * CH) wsout[3 * CH * CH + j] = f2b(wproj[j]);
    }
}

// --- main fused kernel: one workgroup per 32-token block ------------------
// Wave w owns head w. Async-stage structure:
//   top:  ISSUE ef/mask HBM loads into registers (in flight through phase 1)
//   1:    QKV via MFMA (x + weights, L2-hot; weight frags hoisted)
//   st:   write ef (bf16, -inf mask sentinel) to efS LDS     [barrier]
//   2a:   scores^T via MFMA (wave-private)
//   2b:   softmax + gate (ef bf16 from LDS, sentinel mask)
//   3:    PV via MFMA (wave-private)                          [barrier]
//   4:    proj GEMM via MFMA
// LDS: 3x8192 (Rv,Rq,Rk) + efS 8192 = 32768 B.
__launch_bounds__(256, 3)
__global__ void fused_block_attn(
    const float* __restrict__ x,
    const float* __restrict__ edge_feats,
    const float* __restrict__ bqkv,
    const float* __restrict__ bproj,
    const float* __restrict__ wgate,
    const float* __restrict__ bgate,
    const int*   __restrict__ attn_mask,
    const short* __restrict__ wqkv_b,    // [384][128] bf16
    const short* __restrict__ wproj_b,   // [128][128] bf16
    float* __restrict__ out)
{
    const int b    = blockIdx.x;
    const int tid  = threadIdx.x;
    const int lane = tid & 63;
    const int w    = tid >> 6;
    const int lm   = lane & 15;
    const int g    = lane >> 4;
    const int ak   = g * 8;            // k-offset (elements) within K=32
    const int rb   = g * 4;            // D-row base within tile

    __shared__ short Rv[4096];
    __shared__ short Rq[4096];
    __shared__ short Rk[4096];
    __shared__ short efS[4096];        // bf16 ef: [r][chunk^(r&15)][8]
    short* vt = Rv + w * 1024;
    short* qc = Rq + w * 1024;
    short* kc = Rk + w * 1024;

    // ---- top: ISSUE the HBM ef/mask stream (consumed after phase 1) ------
    const int pr = tid >> 3;           // row 0..31
    const int pu = tid & 7;            // s-group; s = pu*4 .. pu*4+3
    const float* efp = edge_feats + ((size_t)(b * BS + pr) * 33 + pu * 4) * 4;
    f32x4 efv[4];
    efv[0] = ((const f32x4*)efp)[0];
    efv[1] = ((const f32x4*)efp)[1];
    efv[2] = ((const f32x4*)efp)[2];
    efv[3] = ((const f32x4*)efp)[3];
    const i32x4 mkv = *(const i32x4*)(attn_mask + (size_t)(b * BS + pr) * 33 + pu * 4);

    // ---- Phase 1: own-head QKV via MFMA (x + weights all L2-hot) ---------
    const float* xb = x + (size_t)b * (BS * CH);
    bf16x8 kvf[2][4];
    #pragma unroll
    for (int kk = 0; kk < 4; ++kk) {
        const float* p0 = xb + lm * CH + kk * 32 + ak;
        const float* p1 = p0 + 16 * CH;
        kvf[0][kk] = pack8(*(const f32x4*)p0, *(const f32x4*)(p0 + 4));
        kvf[1][kk] = pack8(*(const f32x4*)p1, *(const f32x4*)(p1 + 4));
    }

    // hoist all q/k weight fragments (4 tiles x 4 frags) before any MFMA
    bf16x8 wfa[4][4];
    #pragma unroll
    for (int t = 0; t < 4; ++t) {
        const int o0 = ((t >> 1) ? CH : 0) + w * 32 + (t & 1) * 16;
        const short* wp = wqkv_b + (o0 + lm) * CH + ak;
        #pragma unroll
        for (int kk = 0; kk < 4; ++kk) wfa[t][kk] = *(const bf16x8*)(wp + kk * 32);
    }
    #pragma unroll
    for (int t = 0; t < 4; ++t) {          // q0,q1,k0,k1 (swapped orient)
        const int o0 = ((t >> 1) ? CH : 0) + w * 32 + (t & 1) * 16;
        f32x4 acc0 = *(const f32x4*)(bqkv + o0 + rb);
        f32x4 acc1 = acc0;
        #pragma unroll
        for (int kk = 0; kk < 4; ++kk) {
            acc0 = __builtin_amdgcn_mfma_f32_16x16x32_bf16(wfa[t][kk], kvf[0][kk], acc0, 0, 0, 0);
            acc1 = __builtin_amdgcn_mfma_f32_16x16x32_bf16(wfa[t][kk], kvf[1][kk], acc1, 0, 0, 0);
        }
        short* dst = (t >> 1) ? kc : qc;
        const int c0 = (t & 1) * 16 + rb;
        *(u16x4*)&dst[swz(lm, c0)]      = pack4(acc0);
        *(u16x4*)&dst[swz(16 + lm, c0)] = pack4(acc1);
    }
    #pragma unroll
    for (int t = 0; t < 2; ++t) {          // v0,v1 (normal orient -> V^T)
        const int o0 = 2 * CH + w * 32 + t * 16;
        const short* wp = wqkv_b + (o0 + lm) * CH + ak;
        bf16x8 wf[4];
        #pragma unroll
        for (int kk = 0; kk < 4; ++kk) wf[kk] = *(const bf16x8*)(wp + kk * 32);
        float bv = bqkv[o0 + lm];
        f32x4 acc0 = {bv, bv, bv, bv};
        f32x4 acc1 = acc0;
        #pragma unroll
        for (int kk = 0; kk < 4; ++kk) {
            acc0 = __builtin_amdgcn_mfma_f32_16x16x32_bf16(kvf[0][kk], wf[kk], acc0, 0, 0, 0);
            acc1 = __builtin_amdgcn_mfma_f32_16x16x32_bf16(kvf[1][kk], wf[kk], acc1, 0, 0, 0);
        }
        const int row = t * 16 + lm;
        *(u16x4*)&vt[swz(row, rb)]      = pack4(acc0);
        *(u16x4*)&vt[swz(row, 16 + rb)] = pack4(acc1);
    }

    // ---- stage bf16 ef (loads long since returned); masked -> -inf -------
    {
        #pragma unroll
        for (int jj = 0; jj < 2; ++jj) {         // chunk = pu*2 + jj
            bf16x8 st;
            #pragma unroll
            for (int h2 = 0; h2 < 2; ++h2) {     // s within chunk
                const int s = pu * 4 + jj * 2 + h2;
                f32x4 e = efv[jj * 2 + h2];
                if (s == pr) { e[0] = 0.f; e[1] = 0.f; e[2] = 0.f; e[3] = 1.f; }
                const float e3 = mkv[jj * 2 + h2] ? e[3] : -INFINITY;
                st[h2 * 4 + 0] = f2b(e[0]);
                st[h2 * 4 + 1] = f2b(e[1]);
                st[h2 * 4 + 2] = f2b(e[2]);
                st[h2 * 4 + 3] = f2b(e3);
            }
            const int chunk = pu * 2 + jj;
            *(bf16x8*)&efS[pr * 128 + ((chunk ^ (pr & 15)) << 3)] = st;
        }
    }
    __syncthreads();

    // ---- Phase 2a: scores^T = K @ Q^T (wave-private) ----------------------
    {
        bf16x8 af0 = *(const bf16x8*)&kc[swz(lm, ak)];
        bf16x8 af1 = *(const bf16x8*)&kc[swz(16 + lm, ak)];
        bf16x8 bq0 = *(const bf16x8*)&qc[swz(lm, ak)];
        bf16x8 bq1 = *(const bf16x8*)&qc[swz(16 + lm, ak)];
        f32x4 z = {0.f, 0.f, 0.f, 0.f};
        f32x4 s00 = __builtin_amdgcn_mfma_f32_16x16x32_bf16(af0, bq0, z, 0, 0, 0);
        f32x4 s10 = __builtin_amdgcn_mfma_f32_16x16x32_bf16(af1, bq0, z, 0, 0, 0);
        f32x4 s01 = __builtin_amdgcn_mfma_f32_16x16x32_bf16(af0, bq1, z, 0, 0, 0);
        f32x4 s11 = __builtin_amdgcn_mfma_f32_16x16x32_bf16(af1, bq1, z, 0, 0, 0);
        const float SC = 0.17677669529663689f;
        *(u16x4*)&kc[swz(lm, rb)]           = pack4(s00 * SC);
        *(u16x4*)&kc[swz(lm, 16 + rb)]      = pack4(s10 * SC);
        *(u16x4*)&kc[swz(16 + lm, rb)]      = pack4(s01 * SC);
        *(u16x4*)&kc[swz(16 + lm, 16 + rb)] = pack4(s11 * SC);
    }

    // ---- Phase 2b: softmax + gate (ef bf16, sentinel-masked) --------------
    {
        const int r    = lane >> 1;
        const int half = lane & 1;
        bf16x8 t0 = *(const bf16x8*)&kc[swz(r, half * 16)];
        bf16x8 t1 = *(const bf16x8*)&kc[swz(r, half * 16 + 8)];

        float dv[16];
        #pragma unroll
        for (int j = 0; j < 8; ++j) {
            dv[j]     = b2f((unsigned short)t0[j]);
            dv[8 + j] = b2f((unsigned short)t1[j]);
        }
        float sd = 0.f;
        #pragma unroll
        for (int j = 0; j < 16; ++j) sd += dv[j];
        sd += __shfl_xor(sd, 1);
        const float d32 = sd * 0.03125f;

        f32x4 wg = *(const f32x4*)(wgate + w * 4);
        float bg = bgate[w];

        float e[16], lw[16];
        float se = 0.f;
        #pragma unroll
        for (int pk = 0; pk < 8; ++pk) {
            const int chunk = half * 8 + pk;
            bf16x8 c = *(const bf16x8*)&efS[r * 128 + ((chunk ^ (r & 15)) << 3)];
            #pragma unroll
            for (int h2 = 0; h2 < 2; ++h2) {
                const int idx = pk * 2 + h2;
                const float f0 = b2f((unsigned short)c[h2 * 4 + 0]);
                const float f1 = b2f((unsigned short)c[h2 * 4 + 1]);
                const float f2c = b2f((unsigned short)c[h2 * 4 + 2]);
                const float f3 = b2f((unsigned short)c[h2 * 4 + 3]);
                const bool m = f3 > -1.0e30f;
                lw[idx] = m ? (f0 * wg[0] + f1 * wg[1] + f2c * wg[2] + f3 * wg[3] + bg) : 0.f;
                e[idx]  = __expf(dv[idx] + f3);     // masked: exp(-inf) = 0
                se += e[idx];
            }
        }
        const float e32 = __expf(d32 + 1.0f);       // global token
        const float tot = se + __shfl_xor(se, 1) + e32;
        const float rinv = 1.0f / tot;
        const float add32 = (e32 * rinv + wg[3] + bg) * 0.03125f;

        #pragma unroll
        for (int pk = 0; pk < 4; ++pk) {
            f32x4 v;
            #pragma unroll
            for (int j = 0; j < 4; ++j) {
                int idx = pk * 4 + j;
                v[j] = e[idx] * rinv + lw[idx] + add32;
            }
            *(u16x4*)&kc[swz(r, half * 16 + pk * 4)] = pack4(v);
        }
    }

    // ---- Phase 3: x_out = V^T @ comb^T via MFMA (wave-private) ------------
    {
        bf16x8 av0 = *(const bf16x8*)&vt[swz(lm, ak)];
        bf16x8 av1 = *(const bf16x8*)&vt[swz(16 + lm, ak)];
        bf16x8 bc0 = *(const bf16x8*)&kc[swz(lm, ak)];
        bf16x8 bc1 = *(const bf16x8*)&kc[swz(16 + lm, ak)];
        f32x4 z = {0.f, 0.f, 0.f, 0.f};
        f32x4 x00 = __builtin_amdgcn_mfma_f32_16x16x32_bf16(av0, bc0, z, 0, 0, 0);
        f32x4 x10 = __builtin_amdgcn_mfma_f32_16x16x32_bf16(av1, bc0, z, 0, 0, 0);
        f32x4 x01 = __builtin_amdgcn_mfma_f32_16x16x32_bf16(av0, bc1, z, 0, 0, 0);
        f32x4 x11 = __builtin_amdgcn_mfma_f32_16x16x32_bf16(av1, bc1, z, 0, 0, 0);
        *(u16x4*)&qc[swz(lm, rb)]           = pack4(x00);
        *(u16x4*)&qc[swz(lm, 16 + rb)]      = pack4(x10);
        *(u16x4*)&qc[swz(16 + lm, rb)]      = pack4(x01);
        *(u16x4*)&qc[swz(16 + lm, 16 + rb)] = pack4(x11);
    }

    // ---- prefetch Wproj fragments + bias, then the cross-head barrier -----
    bf16x8 pw[2][4];
    float pb[2];
    #pragma unroll
    for (int t = 0; t < 2; ++t) {
        int col = w * 32 + t * 16 + lm;
        pb[t] = bproj[col];
        #pragma unroll
        for (int kk = 0; kk < 4; ++kk)
            pw[t][kk] = *(const bf16x8*)(wproj_b + col * CH + kk * 32 + ak);
    }
    __syncthreads();

    // ---- Phase 4: out = x_out @ Wproj^T + bproj ---------------------------
    {
        bf16x8 a2[2][4];
        #pragma unroll
        for (int kk = 0; kk < 4; ++kk) {
            a2[0][kk] = *(const bf16x8*)&Rq[kk * 1024 + swz(lm, ak)];
            a2[1][kk] = *(const bf16x8*)&Rq[kk * 1024 + swz(16 + lm, ak)];
        }
        float* ob = out + (size_t)b * BS * CH;
        #pragma unroll
        for (int t = 0; t < 2; ++t) {
            int col = w * 32 + t * 16 + lm;
            f32x4 acc0 = {pb[t], pb[t], pb[t], pb[t]};
            f32x4 acc1 = acc0;
            #pragma unroll
            for (int kk = 0; kk < 4; ++kk) {
                acc0 = __builtin_amdgcn_mfma_f32_16x16x32_bf16(a2[0][kk], pw[t][kk], acc0, 0, 0, 0);
                acc1 = __builtin_amdgcn_mfma_f32_16x16x32_bf16(a2[1][kk], pw[t][kk], acc1, 0, 0, 0);
            }
            #pragma unroll
            for (int j = 0; j < 4; ++j) {
                ob[(rb + j) * CH + col]      = acc0[j];
                ob[(16 + rb + j) * CH + col] = acc1[j];
            }
        }
    }
}

extern "C" void kernel_launch(void* const* d_in, const int* in_sizes, int n_in,
                              void* d_out, int out_size, void* d_ws, size_t ws_size,
                              hipStream_t stream) {
    const float* x          = (const float*)d_in[0];
    const float* edge_feats = (const float*)d_in[1];
    const float* Wqkv       = (const float*)d_in[2];
    const float* bqkv       = (const float*)d_in[3];
    const float* Wproj      = (const float*)d_in[4];
    const float* bproj      = (const float*)d_in[5];
    const float* Wgate      = (const float*)d_in[6];
    const float* bgate      = (const float*)d_in[7];
    const int*   attn_mask  = (const int*)d_in[8];
    float* out = (float*)d_out;
    short* wb  = (short*)d_ws;

    convert_weights<<<256, 256, 0, stream>>>(Wqkv, Wproj, wb);
    fused_block_attn<<<NBLK, 256, 0, stream>>>(
        x, edge_feats, bqkv, bproj, Wgate, bgate, attn_mask,
        wb, wb + 3 * CH * CH, out);
}

// Round 12
// 107.648 us; speedup vs baseline: 1.0021x; 1.0021x over previous
//
#include <hip/hip_runtime.h>
#include <hip/hip_bf16.h>

#define NBLK 4096
#define BS 32
#define CH 128

typedef float f32x4 __attribute__((ext_vector_type(4)));
typedef int   i32x4 __attribute__((ext_vector_type(4)));
typedef short bf16x8 __attribute__((ext_vector_type(8)));
typedef unsigned short u16x4 __attribute__((ext_vector_type(4)));

__device__ __forceinline__ short f2b(float x) {
    return __builtin_bit_cast(short, __float2bfloat16(x));
}
__device__ __forceinline__ float b2f(unsigned short h) {
    union { unsigned u; float f; } c; c.u = ((unsigned)h) << 16; return c.f;
}
__device__ __forceinline__ u16x4 pack4(f32x4 a) {
    u16x4 o;
    o[0] = (unsigned short)f2b(a[0]); o[1] = (unsigned short)f2b(a[1]);
    o[2] = (unsigned short)f2b(a[2]); o[3] = (unsigned short)f2b(a[3]);
    return o;
}
__device__ __forceinline__ bf16x8 pack8(f32x4 a, f32x4 b) {
    bf16x8 o;
    o[0] = f2b(a[0]); o[1] = f2b(a[1]); o[2] = f2b(a[2]); o[3] = f2b(a[3]);
    o[4] = f2b(b[0]); o[5] = f2b(b[1]); o[6] = f2b(b[2]); o[7] = f2b(b[3]);
    return o;
}
// swizzled index (shorts) within a [32 rows][32 cols] bf16 head-chunk (2KB)
__device__ __forceinline__ int swz(int row, int col) {
    return (row << 5) + ((((col >> 3) ^ ((row >> 1) & 3)) << 3) | (col & 7));
}

// --- pre-kernel: convert weights to bf16 into workspace -------------------
__global__ void convert_weights(const float* __restrict__ wqkv,
                                const float* __restrict__ wproj,
                                short* __restrict__ wsout) {
    int i = blockIdx.x * 256 + threadIdx.x;          // 0 .. 65535
    if (i < 3 * CH * CH) {
        wsout[i] = f2b(wqkv[i]);
    } else {
        int j = i - 3 * CH * CH;
        if (j < CH * CH) wsout[3 * CH * CH + j] = f2b(wproj[j]);
    }
}

// --- main fused kernel: one workgroup per 32-token block ------------------
// Wave w owns head w. Async-stage structure:
//   top:  ISSUE ef/mask HBM loads into registers (in flight through phase 1)
//   1:    QKV via MFMA (x + weights, L2-hot; weight frags hoisted)
//   st:   write ef (bf16, -inf mask sentinel) to efS LDS     [barrier]
//   2a:   scores^T via MFMA (wave-private)
//   2b:   softmax + gate (ef bf16 from LDS, sentinel mask)
//   3:    PV via MFMA (wave-private)                          [barrier]
//   4:    proj GEMM via MFMA
// LDS: 3x8192 (Rv,Rq,Rk) + efS 8192 = 32768 B.
__launch_bounds__(256, 3)
__global__ void fused_block_attn(
    const float* __restrict__ x,
    const float* __restrict__ edge_feats,
    const float* __restrict__ bqkv,
    const float* __restrict__ bproj,
    const float* __restrict__ wgate,
    const float* __restrict__ bgate,
    const int*   __restrict__ attn_mask,
    const short* __restrict__ wqkv_b,    // [384][128] bf16
    const short* __restrict__ wproj_b,   // [128][128] bf16
    float* __restrict__ out)
{
    const int b    = blockIdx.x;
    const int tid  = threadIdx.x;
    const int lane = tid & 63;
    const int w    = tid >> 6;
    const int lm   = lane & 15;
    const int g    = lane >> 4;
    const int ak   = g * 8;            // k-offset (elements) within K=32
    const int rb   = g * 4;            // D-row base within tile

    __shared__ short Rv[4096];
    __shared__ short Rq[4096];
    __shared__ short Rk[4096];
    __shared__ short efS[4096];        // bf16 ef: [r][chunk^(r&15)][8]
    short* vt = Rv + w * 1024;
    short* qc = Rq + w * 1024;
    short* kc = Rk + w * 1024;

    // ---- top: ISSUE the HBM ef/mask stream (consumed after phase 1) ------
    const int pr = tid >> 3;           // row 0..31
    const int pu = tid & 7;            // s-group; s = pu*4 .. pu*4+3
    const float* efp = edge_feats + ((size_t)(b * BS + pr) * 33 + pu * 4) * 4;
    f32x4 efv[4];
    efv[0] = ((const f32x4*)efp)[0];
    efv[1] = ((const f32x4*)efp)[1];
    efv[2] = ((const f32x4*)efp)[2];
    efv[3] = ((const f32x4*)efp)[3];
    const i32x4 mkv = *(const i32x4*)(attn_mask + (size_t)(b * BS + pr) * 33 + pu * 4);

    // ---- Phase 1: own-head QKV via MFMA (x + weights all L2-hot) ---------
    const float* xb = x + (size_t)b * (BS * CH);
    bf16x8 kvf[2][4];
    #pragma unroll
    for (int kk = 0; kk < 4; ++kk) {
        const float* p0 = xb + lm * CH + kk * 32 + ak;
        const float* p1 = p0 + 16 * CH;
        kvf[0][kk] = pack8(*(const f32x4*)p0, *(const f32x4*)(p0 + 4));
        kvf[1][kk] = pack8(*(const f32x4*)p1, *(const f32x4*)(p1 + 4));
    }

    // hoist all q/k weight fragments (4 tiles x 4 frags) before any MFMA
    bf16x8 wfa[4][4];
    #pragma unroll
    for (int t = 0; t < 4; ++t) {
        const int o0 = ((t >> 1) ? CH : 0) + w * 32 + (t & 1) * 16;
        const short* wp = wqkv_b + (o0 + lm) * CH + ak;
        #pragma unroll
        for (int kk = 0; kk < 4; ++kk) wfa[t][kk] = *(const bf16x8*)(wp + kk * 32);
    }
    #pragma unroll
    for (int t = 0; t < 4; ++t) {          // q0,q1,k0,k1 (swapped orient)
        const int o0 = ((t >> 1) ? CH : 0) + w * 32 + (t & 1) * 16;
        f32x4 acc0 = *(const f32x4*)(bqkv + o0 + rb);
        f32x4 acc1 = acc0;
        #pragma unroll
        for (int kk = 0; kk < 4; ++kk) {
            acc0 = __builtin_amdgcn_mfma_f32_16x16x32_bf16(wfa[t][kk], kvf[0][kk], acc0, 0, 0, 0);
            acc1 = __builtin_amdgcn_mfma_f32_16x16x32_bf16(wfa[t][kk], kvf[1][kk], acc1, 0, 0, 0);
        }
        short* dst = (t >> 1) ? kc : qc;
        const int c0 = (t & 1) * 16 + rb;
        *(u16x4*)&dst[swz(lm, c0)]      = pack4(acc0);
        *(u16x4*)&dst[swz(16 + lm, c0)] = pack4(acc1);
    }
    #pragma unroll
    for (int t = 0; t < 2; ++t) {          // v0,v1 (normal orient -> V^T)
        const int o0 = 2 * CH + w * 32 + t * 16;
        const short* wp = wqkv_b + (o0 + lm) * CH + ak;
        bf16x8 wf[4];
        #pragma unroll
        for (int kk = 0; kk < 4; ++kk) wf[kk] = *(const bf16x8*)(wp + kk * 32);
        float bv = bqkv[o0 + lm];
        f32x4 acc0 = {bv, bv, bv, bv};
        f32x4 acc1 = acc0;
        #pragma unroll
        for (int kk = 0; kk < 4; ++kk) {
            acc0 = __builtin_amdgcn_mfma_f32_16x16x32_bf16(kvf[0][kk], wf[kk], acc0, 0, 0, 0);
            acc1 = __builtin_amdgcn_mfma_f32_16x16x32_bf16(kvf[1][kk], wf[kk], acc1, 0, 0, 0);
        }
        const int row = t * 16 + lm;
        *(u16x4*)&vt[swz(row, rb)]      = pack4(acc0);
        *(u16x4*)&vt[swz(row, 16 + rb)] = pack4(acc1);
    }

    // ---- stage bf16 ef (loads long since returned); masked -> -inf -------
    {
        #pragma unroll
        for (int jj = 0; jj < 2; ++jj) {         // chunk = pu*2 + jj
            bf16x8 st;
            #pragma unroll
            for (int h2 = 0; h2 < 2; ++h2) {     // s within chunk
                const int s = pu * 4 + jj * 2 + h2;
                f32x4 e = efv[jj * 2 + h2];
                if (s == pr) { e[0] = 0.f; e[1] = 0.f; e[2] = 0.f; e[3] = 1.f; }
                const float e3 = mkv[jj * 2 + h2] ? e[3] : -INFINITY;
                st[h2 * 4 + 0] = f2b(e[0]);
                st[h2 * 4 + 1] = f2b(e[1]);
                st[h2 * 4 + 2] = f2b(e[2]);
                st[h2 * 4 + 3] = f2b(e3);
            }
            const int chunk = pu * 2 + jj;
            *(bf16x8*)&efS[pr * 128 + ((chunk ^ (pr & 15)) << 3)] = st;
        }
    }
    __syncthreads();

    // ---- Phase 2a: scores^T = K @ Q^T (wave-private) ----------------------
    {
        bf16x8 af0 = *(const bf16x8*)&kc[swz(lm, ak)];
        bf16x8 af1 = *(const bf16x8*)&kc[swz(16 + lm, ak)];
        bf16x8 bq0 = *(const bf16x8*)&qc[swz(lm, ak)];
        bf16x8 bq1 = *(const bf16x8*)&qc[swz(16 + lm, ak)];
        f32x4 z = {0.f, 0.f, 0.f, 0.f};
        f32x4 s00 = __builtin_amdgcn_mfma_f32_16x16x32_bf16(af0, bq0, z, 0, 0, 0);
        f32x4 s10 = __builtin_amdgcn_mfma_f32_16x16x32_bf16(af1, bq0, z, 0, 0, 0);
        f32x4 s01 = __builtin_amdgcn_mfma_f32_16x16x32_bf16(af0, bq1, z, 0, 0, 0);
        f32x4 s11 = __builtin_amdgcn_mfma_f32_16x16x32_bf16(af1, bq1, z, 0, 0, 0);
        const float SC = 0.17677669529663689f;
        *(u16x4*)&kc[swz(lm, rb)]           = pack4(s00 * SC);
        *(u16x4*)&kc[swz(lm, 16 + rb)]      = pack4(s10 * SC);
        *(u16x4*)&kc[swz(16 + lm, rb)]      = pack4(s01 * SC);
        *(u16x4*)&kc[swz(16 + lm, 16 + rb)] = pack4(s11 * SC);
    }

    // ---- Phase 2b: softmax + gate (ef bf16, sentinel-masked) --------------
    {
        const int r    = lane >> 1;
        const int half = lane & 1;
        bf16x8 t0 = *(const bf16x8*)&kc[swz(r, half * 16)];
        bf16x8 t1 = *(const bf16x8*)&kc[swz(r, half * 16 + 8)];

        float dv[16];
        #pragma unroll
        for (int j = 0; j < 8; ++j) {
            dv[j]     = b2f((unsigned short)t0[j]);
            dv[8 + j] = b2f((unsigned short)t1[j]);
        }
        float sd = 0.f;
        #pragma unroll
        for (int j = 0; j < 16; ++j) sd += dv[j];
        sd += __shfl_xor(sd, 1);
        const float d32 = sd * 0.03125f;

        f32x4 wg = *(const f32x4*)(wgate + w * 4);
        float bg = bgate[w];

        float e[16], lw[16];
        float se = 0.f;
        #pragma unroll
        for (int pk = 0; pk < 8; ++pk) {
            const int chunk = half * 8 + pk;
            bf16x8 c = *(const bf16x8*)&efS[r * 128 + ((chunk ^ (r & 15)) << 3)];
            #pragma unroll
            for (int h2 = 0; h2 < 2; ++h2) {
                const int idx = pk * 2 + h2;
                const float f0 = b2f((unsigned short)c[h2 * 4 + 0]);
                const float f1 = b2f((unsigned short)c[h2 * 4 + 1]);
                const float f2c = b2f((unsigned short)c[h2 * 4 + 2]);
                const float f3 = b2f((unsigned short)c[h2 * 4 + 3]);
                const bool m = f3 > -1.0e30f;
                lw[idx] = m ? (f0 * wg[0] + f1 * wg[1] + f2c * wg[2] + f3 * wg[3] + bg) : 0.f;
                e[idx]  = __expf(dv[idx] + f3);     // masked: exp(-inf) = 0
                se += e[idx];
            }
        }
        const float e32 = __expf(d32 + 1.0f);       // global token
        const float tot = se + __shfl_xor(se, 1) + e32;
        const float rinv = 1.0f / tot;
        const float add32 = (e32 * rinv + wg[3] + bg) * 0.03125f;

        #pragma unroll
        for (int pk = 0; pk < 4; ++pk) {
            f32x4 v;
            #pragma unroll
            for (int j = 0; j < 4; ++j) {
                int idx = pk * 4 + j;
                v[j] = e[idx] * rinv + lw[idx] + add32;
            }
            *(u16x4*)&kc[swz(r, half * 16 + pk * 4)] = pack4(v);
        }
    }

    // ---- Phase 3: x_out = V^T @ comb^T via MFMA (wave-private) ------------
    {
        bf16x8 av0 = *(const bf16x8*)&vt[swz(lm, ak)];
        bf16x8 av1 = *(const bf16x8*)&vt[swz(16 + lm, ak)];
        bf16x8 bc0 = *(const bf16x8*)&kc[swz(lm, ak)];
        bf16x8 bc1 = *(const bf16x8*)&kc[swz(16 + lm, ak)];
        f32x4 z = {0.f, 0.f, 0.f, 0.f};
        f32x4 x00 = __builtin_amdgcn_mfma_f32_16x16x32_bf16(av0, bc0, z, 0, 0, 0);
        f32x4 x10 = __builtin_amdgcn_mfma_f32_16x16x32_bf16(av1, bc0, z, 0, 0, 0);
        f32x4 x01 = __builtin_amdgcn_mfma_f32_16x16x32_bf16(av0, bc1, z, 0, 0, 0);
        f32x4 x11 = __builtin_amdgcn_mfma_f32_16x16x32_bf16(av1, bc1, z, 0, 0, 0);
        *(u16x4*)&qc[swz(lm, rb)]           = pack4(x00);
        *(u16x4*)&qc[swz(lm, 16 + rb)]      = pack4(x10);
        *(u16x4*)&qc[swz(16 + lm, rb)]      = pack4(x01);
        *(u16x4*)&qc[swz(16 + lm, 16 + rb)] = pack4(x11);
    }

    // ---- prefetch Wproj fragments + bias, then the cross-head barrier -----
    bf16x8 pw[2][4];
    float pb[2];
    #pragma unroll
    for (int t = 0; t < 2; ++t) {
        int col = w * 32 + t * 16 + lm;
        pb[t] = bproj[col];
        #pragma unroll
        for (int kk = 0; kk < 4; ++kk)
            pw[t][kk] = *(const bf16x8*)(wproj_b + col * CH + kk * 32 + ak);
    }
    __syncthreads();

    // ---- Phase 4: out = x_out @ Wproj^T + bproj ---------------------------
    {
        bf16x8 a2[2][4];
        #pragma unroll
        for (int kk = 0; kk < 4; ++kk) {
            a2[0][kk] = *(const bf16x8*)&Rq[kk * 1024 + swz(lm, ak)];
            a2[1][kk] = *(const bf16x8*)&Rq[kk * 1024 + swz(16 + lm, ak)];
        }
        float* ob = out + (size_t)b * BS * CH;
        #pragma unroll
        for (int t = 0; t < 2; ++t) {
            int col = w * 32 + t * 16 + lm;
            f32x4 acc0 = {pb[t], pb[t], pb[t], pb[t]};
            f32x4 acc1 = acc0;
            #pragma unroll
            for (int kk = 0; kk < 4; ++kk) {
                acc0 = __builtin_amdgcn_mfma_f32_16x16x32_bf16(a2[0][kk], pw[t][kk], acc0, 0, 0, 0);
                acc1 = __builtin_amdgcn_mfma_f32_16x16x32_bf16(a2[1][kk], pw[t][kk], acc1, 0, 0, 0);
            }
            #pragma unroll
            for (int j = 0; j < 4; ++j) {
                ob[(rb + j) * CH + col]      = acc0[j];
                ob[(16 + rb + j) * CH + col] = acc1[j];
            }
        }
    }
}

extern "C" void kernel_launch(void* const* d_in, const int* in_sizes, int n_in,
                              void* d_out, int out_size, void* d_ws, size_t ws_size,
                              hipStream_t stream) {
    const float* x          = (const float*)d_in[0];
    const float* edge_feats = (const float*)d_in[1];
    const float* Wqkv       = (const float*)d_in[2];
    const float* bqkv       = (const float*)d_in[3];
    const float* Wproj      = (const float*)d_in[4];
    const float* bproj      = (const float*)d_in[5];
    const float* Wgate      = (const float*)d_in[6];
    const float* bgate      = (const float*)d_in[7];
    const int*   attn_mask  = (const int*)d_in[8];
    float* out = (float*)d_out;
    short* wb  = (short*)d_ws;

    convert_weights<<<256, 256, 0, stream>>>(Wqkv, Wproj, wb);
    fused_block_attn<<<NBLK, 256, 0, stream>>>(
        x, edge_feats, bqkv, bproj, Wgate, bgate, attn_mask,
        wb, wb + 3 * CH * CH, out);
}

// Round 13
// 91.607 us; speedup vs baseline: 1.1776x; 1.1751x over previous
//
#include <hip/hip_runtime.h>
#include <hip/hip_bf16.h>

#define NBLK 4096
#define BS 32
#define CH 128

typedef float f32x4 __attribute__((ext_vector_type(4)));
typedef int   i32x4 __attribute__((ext_vector_type(4)));
typedef int   i32x2 __attribute__((ext_vector_type(2)));
typedef short bf16x8 __attribute__((ext_vector_type(8)));
typedef unsigned short u16x4 __attribute__((ext_vector_type(4)));

__device__ __forceinline__ short f2b(float x) {
    return __builtin_bit_cast(short, __float2bfloat16(x));
}
__device__ __forceinline__ float b2f(unsigned short h) {
    union { unsigned u; float f; } c; c.u = ((unsigned)h) << 16; return c.f;
}
__device__ __forceinline__ u16x4 pack4(f32x4 a) {
    u16x4 o;
    o[0] = (unsigned short)f2b(a[0]); o[1] = (unsigned short)f2b(a[1]);
    o[2] = (unsigned short)f2b(a[2]); o[3] = (unsigned short)f2b(a[3]);
    return o;
}
__device__ __forceinline__ bf16x8 pack8(f32x4 a, f32x4 b) {
    bf16x8 o;
    o[0] = f2b(a[0]); o[1] = f2b(a[1]); o[2] = f2b(a[2]); o[3] = f2b(a[3]);
    o[4] = f2b(b[0]); o[5] = f2b(b[1]); o[6] = f2b(b[2]); o[7] = f2b(b[3]);
    return o;
}
// swizzled index (shorts) within a [32 rows][32 cols] bf16 head-chunk (2KB)
__device__ __forceinline__ int swz(int row, int col) {
    return (row << 5) + ((((col >> 3) ^ ((row >> 1) & 3)) << 3) | (col & 7));
}
__device__ __forceinline__ int shfl64(int v, int sl) { return __shfl(v, sl, 64); }

// --- pre-kernel: convert weights to bf16 into workspace -------------------
__global__ void convert_weights(const float* __restrict__ wqkv,
                                const float* __restrict__ wproj,
                                short* __restrict__ wsout) {
    int i = blockIdx.x * 256 + threadIdx.x;          // 0 .. 65535
    if (i < 3 * CH * CH) {
        wsout[i] = f2b(wqkv[i]);
    } else {
        int j = i - 3 * CH * CH;
        if (j < CH * CH) wsout[3 * CH * CH + j] = f2b(wproj[j]);
    }
}

// --- main fused kernel: one workgroup per TWO token-blocks ----------------
// Wave w owns head w of BOTH blocks (two independent latency chains/wave).
// Weight fragments (wf, pw) loaded once, shared by both blocks' MFMAs.
// V^T never touches LDS: PV A-frags built from phase-1 acc regs via shfl.
// LDS: Rq 16K + Rk 16K + efS 16K = 48 KB -> 3 WG/CU (12 waves, 24 chains).
__launch_bounds__(256, 3)
__global__ void fused_block_attn(
    const float* __restrict__ x,
    const float* __restrict__ edge_feats,
    const float* __restrict__ bqkv,
    const float* __restrict__ bproj,
    const float* __restrict__ wgate,
    const float* __restrict__ bgate,
    const int*   __restrict__ attn_mask,
    const short* __restrict__ wqkv_b,    // [384][128] bf16
    const short* __restrict__ wproj_b,   // [128][128] bf16
    float* __restrict__ out)
{
    const int bp   = blockIdx.x;         // block pair: blocks 2bp, 2bp+1
    const int tid  = threadIdx.x;
    const int lane = tid & 63;
    const int w    = tid >> 6;
    const int lm   = lane & 15;
    const int g    = lane >> 4;
    const int ak   = g * 8;              // k-offset (elements) within K=32
    const int rb   = g * 4;              // D-row base within tile

    __shared__ short Rq[8192];           // [blk][head][32][32] q -> x_out
    __shared__ short Rk[8192];           // [blk][head][32][32] k -> comb
    __shared__ short efS[8192];          // [blk][r][chunk^(r&15)][8] bf16 ef

    // ---- stage ef/mask for both blocks (HBM stream issued first) ---------
    const int pr = tid >> 3;             // row 0..31
    const int pu = tid & 7;              // s-group; s = pu*4 .. pu*4+3
    {
        f32x4 efv[2][4];
        i32x4 mkv[2];
        #pragma unroll
        for (int blk = 0; blk < 2; ++blk) {
            const size_t row = (size_t)((2 * bp + blk) * BS + pr);
            const float* efp = edge_feats + (row * 33 + pu * 4) * 4;
            efv[blk][0] = ((const f32x4*)efp)[0];
            efv[blk][1] = ((const f32x4*)efp)[1];
            efv[blk][2] = ((const f32x4*)efp)[2];
            efv[blk][3] = ((const f32x4*)efp)[3];
            mkv[blk] = *(const i32x4*)(attn_mask + row * 33 + pu * 4);
        }
        #pragma unroll
        for (int blk = 0; blk < 2; ++blk) {
            #pragma unroll
            for (int jj = 0; jj < 2; ++jj) {     // chunk = pu*2 + jj
                bf16x8 st;
                #pragma unroll
                for (int h2 = 0; h2 < 2; ++h2) { // s within chunk
                    const int s = pu * 4 + jj * 2 + h2;
                    f32x4 e = efv[blk][jj * 2 + h2];
                    if (s == pr) { e[0] = 0.f; e[1] = 0.f; e[2] = 0.f; e[3] = 1.f; }
                    const float e3 = mkv[blk][jj * 2 + h2] ? e[3] : -INFINITY;
                    st[h2 * 4 + 0] = f2b(e[0]);
                    st[h2 * 4 + 1] = f2b(e[1]);
                    st[h2 * 4 + 2] = f2b(e[2]);
                    st[h2 * 4 + 3] = f2b(e3);
                }
                const int chunk = pu * 2 + jj;
                *(bf16x8*)&efS[blk * 4096 + pr * 128 + ((chunk ^ (pr & 15)) << 3)] = st;
            }
        }
    }

    // ---- Phase 1: QKV via MFMA, both blocks, shared weight frags ---------
    bf16x8 kvf[2][2][4];
    #pragma unroll
    for (int blk = 0; blk < 2; ++blk) {
        const float* xb = x + (size_t)(2 * bp + blk) * (BS * CH);
        #pragma unroll
        for (int kk = 0; kk < 4; ++kk) {
            const float* p0 = xb + lm * CH + kk * 32 + ak;
            const float* p1 = p0 + 16 * CH;
            kvf[blk][0][kk] = pack8(*(const f32x4*)p0, *(const f32x4*)(p0 + 4));
            kvf[blk][1][kk] = pack8(*(const f32x4*)p1, *(const f32x4*)(p1 + 4));
        }
    }

    #pragma unroll
    for (int t = 0; t < 4; ++t) {          // q0,q1,k0,k1 (swapped orient)
        const int o0 = ((t >> 1) ? CH : 0) + w * 32 + (t & 1) * 16;
        const short* wp = wqkv_b + (o0 + lm) * CH + ak;
        bf16x8 wf[4];
        #pragma unroll
        for (int kk = 0; kk < 4; ++kk) wf[kk] = *(const bf16x8*)(wp + kk * 32);
        const f32x4 bias = *(const f32x4*)(bqkv + o0 + rb);
        #pragma unroll
        for (int blk = 0; blk < 2; ++blk) {
            f32x4 acc0 = bias, acc1 = bias;
            #pragma unroll
            for (int kk = 0; kk < 4; ++kk) {
                acc0 = __builtin_amdgcn_mfma_f32_16x16x32_bf16(wf[kk], kvf[blk][0][kk], acc0, 0, 0, 0);
                acc1 = __builtin_amdgcn_mfma_f32_16x16x32_bf16(wf[kk], kvf[blk][1][kk], acc1, 0, 0, 0);
            }
            short* dst = ((t >> 1) ? Rk : Rq) + blk * 4096 + w * 1024;
            const int c0 = (t & 1) * 16 + rb;
            *(u16x4*)&dst[swz(lm, c0)]      = pack4(acc0);
            *(u16x4*)&dst[swz(16 + lm, c0)] = pack4(acc1);
        }
    }
    // v tiles: keep V^T packed in registers (no LDS round-trip)
    // vtp[blk][t][a]: a=0 -> V[tokens 4g..4g+3][dim t*16+lm]
    //                 a=1 -> V[tokens 16+4g..+3][dim t*16+lm]   (2 dwords each)
    i32x2 vtp[2][2][2];
    #pragma unroll
    for (int t = 0; t < 2; ++t) {
        const int o0 = 2 * CH + w * 32 + t * 16;
        const short* wp = wqkv_b + (o0 + lm) * CH + ak;
        bf16x8 wf[4];
        #pragma unroll
        for (int kk = 0; kk < 4; ++kk) wf[kk] = *(const bf16x8*)(wp + kk * 32);
        const float bv = bqkv[o0 + lm];
        #pragma unroll
        for (int blk = 0; blk < 2; ++blk) {
            f32x4 acc0 = {bv, bv, bv, bv};
            f32x4 acc1 = acc0;
            #pragma unroll
            for (int kk = 0; kk < 4; ++kk) {
                acc0 = __builtin_amdgcn_mfma_f32_16x16x32_bf16(kvf[blk][0][kk], wf[kk], acc0, 0, 0, 0);
                acc1 = __builtin_amdgcn_mfma_f32_16x16x32_bf16(kvf[blk][1][kk], wf[kk], acc1, 0, 0, 0);
            }
            vtp[blk][t][0] = __builtin_bit_cast(i32x2, pack4(acc0));
            vtp[blk][t][1] = __builtin_bit_cast(i32x2, pack4(acc1));
        }
    }
    __syncthreads();   // guards efS (written at top) for phase 2b

    // ---- Phase 2a: scores^T = K @ Q^T (wave-private, both blocks) --------
    #pragma unroll
    for (int blk = 0; blk < 2; ++blk) {
        short* kc = Rk + blk * 4096 + w * 1024;
        short* qc = Rq + blk * 4096 + w * 1024;
        bf16x8 af0 = *(const bf16x8*)&kc[swz(lm, ak)];
        bf16x8 af1 = *(const bf16x8*)&kc[swz(16 + lm, ak)];
        bf16x8 bq0 = *(const bf16x8*)&qc[swz(lm, ak)];
        bf16x8 bq1 = *(const bf16x8*)&qc[swz(16 + lm, ak)];
        f32x4 z = {0.f, 0.f, 0.f, 0.f};
        f32x4 s00 = __builtin_amdgcn_mfma_f32_16x16x32_bf16(af0, bq0, z, 0, 0, 0);
        f32x4 s10 = __builtin_amdgcn_mfma_f32_16x16x32_bf16(af1, bq0, z, 0, 0, 0);
        f32x4 s01 = __builtin_amdgcn_mfma_f32_16x16x32_bf16(af0, bq1, z, 0, 0, 0);
        f32x4 s11 = __builtin_amdgcn_mfma_f32_16x16x32_bf16(af1, bq1, z, 0, 0, 0);
        const float SC = 0.17677669529663689f;
        *(u16x4*)&kc[swz(lm, rb)]           = pack4(s00 * SC);
        *(u16x4*)&kc[swz(lm, 16 + rb)]      = pack4(s10 * SC);
        *(u16x4*)&kc[swz(16 + lm, rb)]      = pack4(s01 * SC);
        *(u16x4*)&kc[swz(16 + lm, 16 + rb)] = pack4(s11 * SC);
    }

    // ---- Phase 2b: softmax + gate (wave-private, both blocks) ------------
    #pragma unroll
    for (int blk = 0; blk < 2; ++blk) {
        short* kc = Rk + blk * 4096 + w * 1024;
        const short* efSb = efS + blk * 4096;
        const int r    = lane >> 1;
        const int half = lane & 1;
        bf16x8 t0 = *(const bf16x8*)&kc[swz(r, half * 16)];
        bf16x8 t1 = *(const bf16x8*)&kc[swz(r, half * 16 + 8)];

        float dv[16];
        #pragma unroll
        for (int j = 0; j < 8; ++j) {
            dv[j]     = b2f((unsigned short)t0[j]);
            dv[8 + j] = b2f((unsigned short)t1[j]);
        }
        float sd = 0.f;
        #pragma unroll
        for (int j = 0; j < 16; ++j) sd += dv[j];
        sd += __shfl_xor(sd, 1);
        const float d32 = sd * 0.03125f;

        f32x4 wg = *(const f32x4*)(wgate + w * 4);
        float bg = bgate[w];

        float e[16], lw[16];
        float se = 0.f;
        #pragma unroll
        for (int pk = 0; pk < 8; ++pk) {
            const int chunk = half * 8 + pk;
            bf16x8 c = *(const bf16x8*)&efSb[r * 128 + ((chunk ^ (r & 15)) << 3)];
            #pragma unroll
            for (int h2 = 0; h2 < 2; ++h2) {
                const int idx = pk * 2 + h2;
                const float f0 = b2f((unsigned short)c[h2 * 4 + 0]);
                const float f1 = b2f((unsigned short)c[h2 * 4 + 1]);
                const float f2c = b2f((unsigned short)c[h2 * 4 + 2]);
                const float f3 = b2f((unsigned short)c[h2 * 4 + 3]);
                const bool m = f3 > -1.0e30f;
                lw[idx] = m ? (f0 * wg[0] + f1 * wg[1] + f2c * wg[2] + f3 * wg[3] + bg) : 0.f;
                e[idx]  = __expf(dv[idx] + f3);     // masked: exp(-inf) = 0
                se += e[idx];
            }
        }
        const float e32 = __expf(d32 + 1.0f);       // global token
        const float tot = se + __shfl_xor(se, 1) + e32;
        const float rinv = 1.0f / tot;
        const float add32 = (e32 * rinv + wg[3] + bg) * 0.03125f;

        #pragma unroll
        for (int pk = 0; pk < 4; ++pk) {
            f32x4 v;
            #pragma unroll
            for (int j = 0; j < 4; ++j) {
                int idx = pk * 4 + j;
                v[j] = e[idx] * rinv + lw[idx] + add32;
            }
            *(u16x4*)&kc[swz(r, half * 16 + pk * 4)] = pack4(v);
        }
    }

    // ---- Phase 3: PV via MFMA; V^T A-frags built from regs via shfl -------
    const int srcA = lm + 16 * ((2 * g) & 3);
    const int srcB = lm + 16 * ((2 * g + 1) & 3);
    #pragma unroll
    for (int blk = 0; blk < 2; ++blk) {
        short* kc = Rk + blk * 4096 + w * 1024;
        short* qc = Rq + blk * 4096 + w * 1024;
        bf16x8 av[2];
        #pragma unroll
        for (int t = 0; t < 2; ++t) {
            const i32x2 pa = vtp[blk][t][0];     // tokens 4g'..4g'+3
            const i32x2 pb2 = vtp[blk][t][1];    // tokens 16+4g'..+3
            const int a0x = shfl64(pa[0], srcA),  a0y = shfl64(pa[1], srcA);
            const int a1x = shfl64(pb2[0], srcA), a1y = shfl64(pb2[1], srcA);
            const int b0x = shfl64(pa[0], srcB),  b0y = shfl64(pa[1], srcB);
            const int b1x = shfl64(pb2[0], srcB), b1y = shfl64(pb2[1], srcB);
            const bool lo = (g < 2);             // tokens 8g..8g+7 < 16 ?
            i32x4 wv;
            wv[0] = lo ? a0x : a1x;
            wv[1] = lo ? a0y : a1y;
            wv[2] = lo ? b0x : b1x;
            wv[3] = lo ? b0y : b1y;
            av[t] = __builtin_bit_cast(bf16x8, wv);   // V^T[dim t*16+lm][8g..8g+7]
        }
        bf16x8 bc0 = *(const bf16x8*)&kc[swz(lm, ak)];
        bf16x8 bc1 = *(const bf16x8*)&kc[swz(16 + lm, ak)];
        f32x4 z = {0.f, 0.f, 0.f, 0.f};
        f32x4 x00 = __builtin_amdgcn_mfma_f32_16x16x32_bf16(av[0], bc0, z, 0, 0, 0);
        f32x4 x10 = __builtin_amdgcn_mfma_f32_16x16x32_bf16(av[1], bc0, z, 0, 0, 0);
        f32x4 x01 = __builtin_amdgcn_mfma_f32_16x16x32_bf16(av[0], bc1, z, 0, 0, 0);
        f32x4 x11 = __builtin_amdgcn_mfma_f32_16x16x32_bf16(av[1], bc1, z, 0, 0, 0);
        *(u16x4*)&qc[swz(lm, rb)]           = pack4(x00);
        *(u16x4*)&qc[swz(lm, 16 + rb)]      = pack4(x10);
        *(u16x4*)&qc[swz(16 + lm, rb)]      = pack4(x01);
        *(u16x4*)&qc[swz(16 + lm, 16 + rb)] = pack4(x11);
    }

    // ---- prefetch Wproj fragments + bias, then the cross-head barrier -----
    bf16x8 pw[2][4];
    float pb[2];
    #pragma unroll
    for (int t = 0; t < 2; ++t) {
        int col = w * 32 + t * 16 + lm;
        pb[t] = bproj[col];
        #pragma unroll
        for (int kk = 0; kk < 4; ++kk)
            pw[t][kk] = *(const bf16x8*)(wproj_b + col * CH + kk * 32 + ak);
    }
    __syncthreads();

    // ---- Phase 4: out = x_out @ Wproj^T + bproj (both blocks) -------------
    #pragma unroll
    for (int blk = 0; blk < 2; ++blk) {
        bf16x8 a2[2][4];
        #pragma unroll
        for (int kk = 0; kk < 4; ++kk) {
            a2[0][kk] = *(const bf16x8*)&Rq[blk * 4096 + kk * 1024 + swz(lm, ak)];
            a2[1][kk] = *(const bf16x8*)&Rq[blk * 4096 + kk * 1024 + swz(16 + lm, ak)];
        }
        float* ob = out + (size_t)(2 * bp + blk) * BS * CH;
        #pragma unroll
        for (int t = 0; t < 2; ++t) {
            int col = w * 32 + t * 16 + lm;
            f32x4 acc0 = {pb[t], pb[t], pb[t], pb[t]};
            f32x4 acc1 = acc0;
            #pragma unroll
            for (int kk = 0; kk < 4; ++kk) {
                acc0 = __builtin_amdgcn_mfma_f32_16x16x32_bf16(a2[0][kk], pw[t][kk], acc0, 0, 0, 0);
                acc1 = __builtin_amdgcn_mfma_f32_16x16x32_bf16(a2[1][kk], pw[t][kk], acc1, 0, 0, 0);
            }
            #pragma unroll
            for (int j = 0; j < 4; ++j) {
                ob[(rb + j) * CH + col]      = acc0[j];
                ob[(16 + rb + j) * CH + col] = acc1[j];
            }
        }
    }
}

extern "C" void kernel_launch(void* const* d_in, const int* in_sizes, int n_in,
                              void* d_out, int out_size, void* d_ws, size_t ws_size,
                              hipStream_t stream) {
    const float* x          = (const float*)d_in[0];
    const float* edge_feats = (const float*)d_in[1];
    const float* Wqkv       = (const float*)d_in[2];
    const float* bqkv       = (const float*)d_in[3];
    const float* Wproj      = (const float*)d_in[4];
    const float* bproj      = (const float*)d_in[5];
    const float* Wgate      = (const float*)d_in[6];
    const float* bgate      = (const float*)d_in[7];
    const int*   attn_mask  = (const int*)d_in[8];
    float* out = (float*)d_out;
    short* wb  = (short*)d_ws;

    convert_weights<<<256, 256, 0, stream>>>(Wqkv, Wproj, wb);
    fused_block_attn<<<NBLK / 2, 256, 0, stream>>>(
        x, edge_feats, bqkv, bproj, Wgate, bgate, attn_mask,
        wb, wb + 3 * CH * CH, out);
}